// Round 4
// baseline (500.266 us; speedup 1.0000x reference)
//
#include <hip/hip_runtime.h>
#include <cstddef>
#include <cstdint>

typedef unsigned short u16;
typedef unsigned int   u32;
typedef __bf16  bf16x8 __attribute__((ext_vector_type(8)));
typedef float   f32x4  __attribute__((ext_vector_type(4)));

#define DEV __device__ __forceinline__

DEV float b2f(u16 u) { union { u32 i; float f; } c; c.i = ((u32)u) << 16; return c.f; }
DEV u16 f2b(float x) { union { float f; u32 i; } c; c.f = x; u32 b = c.i;
                       return (u16)((b + 0x7FFFu + ((b >> 16) & 1u)) >> 16); }
DEV float sigm(float x)  { return 1.0f / (1.0f + __expf(-x)); }
DEV float tanh_(float x) { return 1.0f - 2.0f / (1.0f + __expf(2.0f * x)); }
DEV float gelu_(float x) { return 0.5f * x * (1.0f + erff(x * 0.70710678118654752f)); }

DEV void u4tof8(uint4 v, float* f) {
    f[0] = b2f((u16)(v.x & 0xFFFF)); f[1] = b2f((u16)(v.x >> 16));
    f[2] = b2f((u16)(v.y & 0xFFFF)); f[3] = b2f((u16)(v.y >> 16));
    f[4] = b2f((u16)(v.z & 0xFFFF)); f[5] = b2f((u16)(v.z >> 16));
    f[6] = b2f((u16)(v.w & 0xFFFF)); f[7] = b2f((u16)(v.w >> 16));
}
DEV uint4 f8tou4(const float* f) {
    uint4 v;
    v.x = (u32)f2b(f[0]) | ((u32)f2b(f[1]) << 16);
    v.y = (u32)f2b(f[2]) | ((u32)f2b(f[3]) << 16);
    v.z = (u32)f2b(f[4]) | ((u32)f2b(f[5]) << 16);
    v.w = (u32)f2b(f[6]) | ((u32)f2b(f[7]) << 16);
    return v;
}

// ---- workspace byte offsets; total 118,546,432 B (fits: 144,113,664 proven) ----
#define OB_X     0ull            // x  [40000][128] bf16 (stage overrun -> FB, safe)
#define OB_FB    10240000ull     // fb [20000][128] bf16 (overrun -> PRU, safe)
#define OB_PRU   15360000ull     // PrU [40000][256] bf16 (= x@Wr^T + urb)
#define OB_H     35840000ull     // h   [40000][256] bf16
#define OB_UH    56320000ull     // Uh  [40000][256] bf16 ; nei overlays after loop
#define OB_SH    76800000ull     // sumh  [40000][256] bf16
#define OB_SGH   97280000ull     // sumgh [40000][256] bf16
#define OB_BZ    117760000ull    // BzT [256][384] bf16 : Wz[:, :111]|pad|Wz[:,111:]
#define OB_BH    117956608ull    // BhT [256][384] bf16
#define OB_BU    118153216ull    // BuT [256][256] bf16
#define OB_BR    118284288ull    // BrT [256][128] bf16 (Wr, K-pad)
#define OB_BO    118349824ull    // BoT [256][384] bf16 : Wo[:, :98]|pad|Wo[:,98:]
#define WS_BYTES 118546432ull

// ---------------------------------------------------------------------------
// Weight repack -> [N][K] bf16. Grid 384x256.
__global__ __launch_bounds__(256) void k_repack(
    const float* __restrict__ Wz, const float* __restrict__ Wr,
    const float* __restrict__ Ur, const float* __restrict__ Wh,
    const float* __restrict__ Wo,
    u16* __restrict__ BzT, u16* __restrict__ BhT, u16* __restrict__ BuT,
    u16* __restrict__ BrT, u16* __restrict__ BoT) {
    int idx = blockIdx.x * 256 + threadIdx.x;   // 0..98303
    {   // [256][384] operands
        int n = idx / 384, k = idx % 384;
        float vz, vh, vo;
        if (k < 111)      { vz = Wz[n * 367 + k];          vh = Wh[n * 367 + k]; }
        else if (k < 128) { vz = 0.0f;                     vh = 0.0f; }
        else              { vz = Wz[n * 367 + k - 17];     vh = Wh[n * 367 + k - 17]; }
        if (k < 98)       vo = Wo[n * 354 + k];
        else if (k < 128) vo = 0.0f;
        else              vo = Wo[n * 354 + k - 30];
        BzT[idx] = f2b(vz); BhT[idx] = f2b(vh); BoT[idx] = f2b(vo);
    }
    if (idx < 65536) {                 // BuT [256][256]
        BuT[idx] = f2b(Ur[idx]);
    }
    if (idx < 32768) {                 // BrT [256][128]
        int n = idx >> 7, k = idx & 127;
        BrT[idx] = f2b(k < 111 ? Wr[n * 111 + k] : 0.0f);
    }
}

// x[e][c] (bf16, [40000][128], zero K-pad). Grid 40000x128.
__global__ void k_build_x(const float* __restrict__ fnode,
                          const float* __restrict__ fmess, u16* __restrict__ x) {
    int e = blockIdx.x, c = threadIdx.x;
    int src = (int)fmess[(size_t)e * 15];
    float v = 0.0f;
    if (c < 98)       v = fnode[(size_t)src * 98 + c];
    else if (c < 111) v = fmess[(size_t)e * 15 + 2 + (c - 98)];
    x[(size_t)e * 128 + c] = f2b(v);
}

// fb [20000][128] bf16 zero-padded. Grid 10000x256.
__global__ __launch_bounds__(256) void k_build_fb(const float* __restrict__ fnode,
                                                  u16* __restrict__ fb) {
    int idx = blockIdx.x * 256 + threadIdx.x;
    int n = idx >> 7, c = idx & 127;
    fb[idx] = f2b(c < 98 ? fnode[(size_t)n * 98 + c] : 0.0f);
}

// ---------------------------------------------------------------------------
// 128x64 bf16 tile stage, XOR-swizzled LDS (byte ^= (row&7)<<4).
DEV void stage128x64(const u16* __restrict__ g, size_t row0, int ld, int k0,
                     u16* s, int tid) {
    #pragma unroll
    for (int it = 0; it < 4; ++it) {
        int r = it * 32 + (tid >> 3);
        int c = (tid & 7) << 3;
        uint4 v = *(const uint4*)(g + (row0 + (size_t)r) * ld + k0 + c);
        int byte = (((r << 6) + c) << 1) ^ ((r & 7) << 4);
        *(uint4*)((char*)s + byte) = v;
    }
}

// Swapped-operand MFMA: acc[i][j] holds C^T fragments ->
// lane holds C[m0+(wr<<6)+16i+(lane&15)][n0+(wc<<6)+16j+((lane>>4)<<2)+reg]
DEV void mma64s(const u16* As, const u16* Bs, f32x4 acc[4][4], int wr, int wc, int lane) {
    int rb = (wr << 6) + (lane & 15);
    int cb = (wc << 6) + (lane & 15);
    int ko = (lane >> 4) << 3;
    #pragma unroll
    for (int kh = 0; kh < 2; ++kh) {
        bf16x8 a[4], b[4];
        #pragma unroll
        for (int i = 0; i < 4; ++i) {
            int ar = rb + (i << 4);
            int ab = (((ar << 6) + (kh << 5) + ko) << 1) ^ ((ar & 7) << 4);
            a[i] = *(const bf16x8*)((const char*)As + ab);
            int br = cb + (i << 4);
            int bb = (((br << 6) + (kh << 5) + ko) << 1) ^ ((br & 7) << 4);
            b[i] = *(const bf16x8*)((const char*)Bs + bb);
        }
        #pragma unroll
        for (int i = 0; i < 4; ++i)
            #pragma unroll
            for (int j = 0; j < 4; ++j)
                acc[i][j] = __builtin_amdgcn_mfma_f32_16x16x32_bf16(b[j], a[i], acc[i][j], 0, 0, 0);
    }
}

#define MG_PROLOG()                                          \
    int tid = threadIdx.x, lane = tid & 63, w = tid >> 6;    \
    int wr = w >> 1, wc = w & 1;                             \
    int bm = blockIdx.x >> 1, bn = blockIdx.x & 1;           \
    size_t m0 = (size_t)bm << 7; int n0 = bn << 7;           \
    int row_l = (wr << 6) + (lane & 15);                     \
    int col_l = (wc << 6) + ((lane >> 4) << 2);

#define ACC_INIT(A)                                          \
    { f32x4 zz = {0.f, 0.f, 0.f, 0.f};                       \
      _Pragma("unroll") for (int i = 0; i < 4; ++i)          \
      _Pragma("unroll") for (int j = 0; j < 4; ++j) A[i][j] = zz; }

// PrU = x @ BrT^T + urb -> bf16. M=40000 N=256 K=128. Grid 313*2.
__global__ __launch_bounds__(256) void k_mg_p(
    const u16* __restrict__ x, const u16* __restrict__ BrT,
    const float* __restrict__ urb, u16* __restrict__ PrU) {
    __shared__ u16 As[8192], Bs[8192];
    MG_PROLOG()
    f32x4 acc[4][4]; ACC_INIT(acc)
    for (int k0 = 0; k0 < 128; k0 += 64) {
        __syncthreads();
        stage128x64(x, m0, 128, k0, As, tid);
        stage128x64(BrT, (size_t)n0, 128, k0, Bs, tid);
        __syncthreads();
        mma64s(As, Bs, acc, wr, wc, lane);
    }
    #pragma unroll
    for (int mi = 0; mi < 4; ++mi) {
        int m = (int)m0 + row_l + (mi << 4);
        if (m >= 40000) continue;
        #pragma unroll
        for (int ni = 0; ni < 4; ++ni) {
            int col = n0 + col_l + (ni << 4);
            float4 ub = *(const float4*)(urb + col);
            ushort4 o;
            o.x = f2b(acc[mi][ni][0] + ub.x); o.y = f2b(acc[mi][ni][1] + ub.y);
            o.z = f2b(acc[mi][ni][2] + ub.z); o.w = f2b(acc[mi][ni][3] + ub.w);
            *(ushort4*)(PrU + (size_t)m * 256 + col) = o;
        }
    }
}

// Depth-1: h = sigm(x@Bzx+bz)*tanh(x@Bhx+bh). Shared-A dual GEMM, K=128. Grid 313*2.
__global__ __launch_bounds__(256) void k_d1(
    const u16* __restrict__ x, const u16* __restrict__ BzT,
    const u16* __restrict__ BhT, const float* __restrict__ bz,
    const float* __restrict__ bh, u16* __restrict__ h) {
    __shared__ u16 As[8192], Bs1[8192], Bs2[8192];
    MG_PROLOG()
    f32x4 aZ[4][4], aH[4][4]; ACC_INIT(aZ) ACC_INIT(aH)
    for (int k0 = 0; k0 < 128; k0 += 64) {
        __syncthreads();
        stage128x64(x, m0, 128, k0, As, tid);
        stage128x64(BzT, (size_t)n0, 384, k0, Bs1, tid);
        stage128x64(BhT, (size_t)n0, 384, k0, Bs2, tid);
        __syncthreads();
        mma64s(As, Bs1, aZ, wr, wc, lane);
        mma64s(As, Bs2, aH, wr, wc, lane);
    }
    #pragma unroll
    for (int mi = 0; mi < 4; ++mi) {
        int m = (int)m0 + row_l + (mi << 4);
        if (m >= 40000) continue;
        #pragma unroll
        for (int ni = 0; ni < 4; ++ni) {
            int col = n0 + col_l + (ni << 4);
            float4 vz = *(const float4*)(bz + col);
            float4 vh = *(const float4*)(bh + col);
            float r[4];
            r[0] = sigm(aZ[mi][ni][0] + vz.x) * tanh_(aH[mi][ni][0] + vh.x);
            r[1] = sigm(aZ[mi][ni][1] + vz.y) * tanh_(aH[mi][ni][1] + vh.y);
            r[2] = sigm(aZ[mi][ni][2] + vz.z) * tanh_(aH[mi][ni][2] + vh.z);
            r[3] = sigm(aZ[mi][ni][3] + vz.w) * tanh_(aH[mi][ni][3] + vh.w);
            if (m == 0) { r[0] = r[1] = r[2] = r[3] = 0.0f; }
            ushort4 o;
            o.x = f2b(r[0]); o.y = f2b(r[1]); o.z = f2b(r[2]); o.w = f2b(r[3]);
            *(ushort4*)(h + (size_t)m * 256 + col) = o;
        }
    }
}

// Uh = h @ BuT^T. M=40000 N=256 K=256. Grid 313*2.
__global__ __launch_bounds__(256) void k_mg_uh(
    const u16* __restrict__ A, const u16* __restrict__ BT, u16* __restrict__ C) {
    __shared__ u16 As[8192], Bs[8192];
    MG_PROLOG()
    f32x4 acc[4][4]; ACC_INIT(acc)
    for (int k0 = 0; k0 < 256; k0 += 64) {
        __syncthreads();
        stage128x64(A, m0, 256, k0, As, tid);
        stage128x64(BT, (size_t)n0, 256, k0, Bs, tid);
        __syncthreads();
        mma64s(As, Bs, acc, wr, wc, lane);
    }
    #pragma unroll
    for (int mi = 0; mi < 4; ++mi) {
        int m = (int)m0 + row_l + (mi << 4);
        if (m >= 40000) continue;
        #pragma unroll
        for (int ni = 0; ni < 4; ++ni) {
            int col = n0 + col_l + (ni << 4);
            ushort4 o;
            o.x = f2b(acc[mi][ni][0]); o.y = f2b(acc[mi][ni][1]);
            o.z = f2b(acc[mi][ni][2]); o.w = f2b(acc[mi][ni][3]);
            *(ushort4*)(C + (size_t)m * 256 + col) = o;
        }
    }
}

// Fused GRU step: z = sigm([x|sumh]@Bz+bz); pre = tanh([x|sumgh]@Bh+bh);
// h = ((1-z)*sumh + z*pre)*emask.  K=384 (x-folded). Grid 313*2. LDS 64KB.
__global__ __launch_bounds__(256) void k_mg_fused(
    const u16* __restrict__ x, const u16* __restrict__ sumh,
    const u16* __restrict__ sumgh, const u16* __restrict__ BzT,
    const u16* __restrict__ BhT, const float* __restrict__ bz,
    const float* __restrict__ bh, u16* __restrict__ h) {
    __shared__ u16 As1[8192], As2[8192], Bs1[8192], Bs2[8192];
    MG_PROLOG()
    f32x4 aZ[4][4], aH[4][4]; ACC_INIT(aZ) ACC_INIT(aH)
    for (int s = 0; s < 6; ++s) {
        int k0 = s << 6;
        __syncthreads();
        if (s < 2) {
            stage128x64(x, m0, 128, k0, As1, tid);
        } else {
            stage128x64(sumh,  m0, 256, k0 - 128, As1, tid);
            stage128x64(sumgh, m0, 256, k0 - 128, As2, tid);
        }
        stage128x64(BzT, (size_t)n0, 384, k0, Bs1, tid);
        stage128x64(BhT, (size_t)n0, 384, k0, Bs2, tid);
        __syncthreads();
        mma64s(As1, Bs1, aZ, wr, wc, lane);
        mma64s(s < 2 ? As1 : As2, Bs2, aH, wr, wc, lane);
    }
    #pragma unroll
    for (int mi = 0; mi < 4; ++mi) {
        int m = (int)m0 + row_l + (mi << 4);
        if (m >= 40000) continue;
        #pragma unroll
        for (int ni = 0; ni < 4; ++ni) {
            int col = n0 + col_l + (ni << 4);
            float4 vz = *(const float4*)(bz + col);
            float4 vh = *(const float4*)(bh + col);
            ushort4 sh4 = *(const ushort4*)(sumh + (size_t)m * 256 + col);
            float shv[4] = {b2f(sh4.x), b2f(sh4.y), b2f(sh4.z), b2f(sh4.w)};
            float bzv[4] = {vz.x, vz.y, vz.z, vz.w};
            float bhv[4] = {vh.x, vh.y, vh.z, vh.w};
            float o[4];
            #pragma unroll
            for (int q = 0; q < 4; ++q) {
                float z   = sigm(aZ[mi][ni][q] + bzv[q]);
                float pre = tanh_(aH[mi][ni][q] + bhv[q]);
                o[q] = (1.0f - z) * shv[q] + z * pre;
            }
            if (m == 0) { o[0] = o[1] = o[2] = o[3] = 0.0f; }
            ushort4 ov;
            ov.x = f2b(o[0]); ov.y = f2b(o[1]); ov.z = f2b(o[2]); ov.w = f2b(o[3]);
            *(ushort4*)(h + (size_t)m * 256 + col) = ov;
        }
    }
}

// out = gelu([fb|nei]@Bo+bo). K=384. M=20000. Grid 157*2. f32 out, row0 masked.
__global__ __launch_bounds__(256) void k_mg_out(
    const u16* __restrict__ fb, const u16* __restrict__ nei,
    const u16* __restrict__ BoT, const float* __restrict__ bo,
    float* __restrict__ out) {
    __shared__ u16 As[8192], Bs[8192];
    MG_PROLOG()
    f32x4 acc[4][4]; ACC_INIT(acc)
    for (int s = 0; s < 6; ++s) {
        int k0 = s << 6;
        __syncthreads();
        if (s < 2) stage128x64(fb,  m0, 128, k0, As, tid);
        else       stage128x64(nei, m0, 256, k0 - 128, As, tid);
        stage128x64(BoT, (size_t)n0, 384, k0, Bs, tid);
        __syncthreads();
        mma64s(As, Bs, acc, wr, wc, lane);
    }
    #pragma unroll
    for (int mi = 0; mi < 4; ++mi) {
        int m = (int)m0 + row_l + (mi << 4);
        if (m >= 20000) continue;
        #pragma unroll
        for (int ni = 0; ni < 4; ++ni) {
            int col = n0 + col_l + (ni << 4);
            float4 vb = *(const float4*)(bo + col);
            float4 o;
            o.x = gelu_(acc[mi][ni][0] + vb.x);
            o.y = gelu_(acc[mi][ni][1] + vb.y);
            o.z = gelu_(acc[mi][ni][2] + vb.z);
            o.w = gelu_(acc[mi][ni][3] + vb.w);
            if (m == 0) { o.x = o.y = o.z = o.w = 0.0f; }
            *(float4*)(out + (size_t)m * 256 + col) = o;
        }
    }
}

// ---------------------------------------------------------------------------
// sumh/sumgh gather. Grid 5000x256 (8 edges/block, 8 bf16/thread).
__global__ __launch_bounds__(256) void k_gather_edge(
    const u16* __restrict__ h, const u16* __restrict__ Uh,
    const u16* __restrict__ PrU, const int* __restrict__ bgraph,
    u16* __restrict__ sumh, u16* __restrict__ sumgh) {
    int e = (blockIdx.x << 3) + (threadIdx.x >> 5);
    int c = (threadIdx.x & 31) << 3;
    size_t o = (size_t)e * 256 + c;
    float pr[8];
    u4tof8(*(const uint4*)(PrU + o), pr);
    float sh[8] = {}, sg[8] = {};
    #pragma unroll
    for (int j = 0; j < 6; ++j) {
        int b = bgraph[e * 6 + j];
        float hv[8], uv[8];
        u4tof8(*(const uint4*)(h  + (size_t)b * 256 + c), hv);
        u4tof8(*(const uint4*)(Uh + (size_t)b * 256 + c), uv);
        #pragma unroll
        for (int q = 0; q < 8; ++q) {
            sh[q] += hv[q];
            sg[q] += sigm(pr[q] + uv[q]) * hv[q];
        }
    }
    *(uint4*)(sumh  + o) = f8tou4(sh);
    *(uint4*)(sumgh + o) = f8tou4(sg);
}

// nei[n] = bf16(sum_j h[agraph[n][j]]). Grid 2500x256.
__global__ __launch_bounds__(256) void k_gather_node(
    const u16* __restrict__ h, const int* __restrict__ agraph,
    u16* __restrict__ nei) {
    int n = (blockIdx.x << 3) + (threadIdx.x >> 5);
    int c = (threadIdx.x & 31) << 3;
    float s[8] = {};
    #pragma unroll
    for (int j = 0; j < 6; ++j) {
        int a = agraph[n * 6 + j];
        float hv[8];
        u4tof8(*(const uint4*)(h + (size_t)a * 256 + c), hv);
        #pragma unroll
        for (int q = 0; q < 8; ++q) s[q] += hv[q];
    }
    *(uint4*)(nei + (size_t)n * 256 + c) = f8tou4(s);
}

// ---------------------------------------------------------------------------
extern "C" void kernel_launch(void* const* d_in, const int* in_sizes, int n_in,
                              void* d_out, int out_size, void* d_ws, size_t ws_size,
                              hipStream_t stream) {
    if (ws_size < WS_BYTES) return;

    const float* fnode  = (const float*)d_in[0];
    const float* fmess  = (const float*)d_in[1];
    const int*   agraph = (const int*)d_in[2];
    const int*   bgraph = (const int*)d_in[3];
    const float* Wz  = (const float*)d_in[4];
    const float* bz  = (const float*)d_in[5];
    const float* Wr  = (const float*)d_in[6];
    const float* Ur  = (const float*)d_in[7];
    const float* urb = (const float*)d_in[8];
    const float* Wh  = (const float*)d_in[9];
    const float* bh  = (const float*)d_in[10];
    const float* Wo  = (const float*)d_in[11];
    const float* bo  = (const float*)d_in[12];

    char* base = (char*)d_ws;
    u16* x     = (u16*)(base + OB_X);
    u16* fb    = (u16*)(base + OB_FB);
    u16* PrU   = (u16*)(base + OB_PRU);
    u16* h     = (u16*)(base + OB_H);
    u16* Uh    = (u16*)(base + OB_UH);
    u16* nei   = (u16*)(base + OB_UH);   // overlay after depth loop
    u16* sumh  = (u16*)(base + OB_SH);
    u16* sumgh = (u16*)(base + OB_SGH);
    u16* BzT   = (u16*)(base + OB_BZ);
    u16* BhT   = (u16*)(base + OB_BH);
    u16* BuT   = (u16*)(base + OB_BU);
    u16* BrT   = (u16*)(base + OB_BR);
    u16* BoT   = (u16*)(base + OB_BO);
    float* out = (float*)d_out;

    hipLaunchKernelGGL(k_repack, dim3(384), dim3(256), 0, stream,
                       Wz, Wr, Ur, Wh, Wo, BzT, BhT, BuT, BrT, BoT);
    hipLaunchKernelGGL(k_build_x, dim3(40000), dim3(128), 0, stream, fnode, fmess, x);
    hipLaunchKernelGGL(k_build_fb, dim3(10000), dim3(256), 0, stream, fnode, fb);
    hipLaunchKernelGGL(k_mg_p, dim3(313 * 2), dim3(256), 0, stream, x, BrT, urb, PrU);
    hipLaunchKernelGGL(k_d1,   dim3(313 * 2), dim3(256), 0, stream, x, BzT, BhT, bz, bh, h);
    for (int d = 1; d < 4; ++d) {
        hipLaunchKernelGGL(k_mg_uh, dim3(313 * 2), dim3(256), 0, stream, h, BuT, Uh);
        hipLaunchKernelGGL(k_gather_edge, dim3(5000), dim3(256), 0, stream,
                           h, Uh, PrU, bgraph, sumh, sumgh);
        hipLaunchKernelGGL(k_mg_fused, dim3(313 * 2), dim3(256), 0, stream,
                           x, sumh, sumgh, BzT, BhT, bz, bh, h);
    }
    hipLaunchKernelGGL(k_gather_node, dim3(2500), dim3(256), 0, stream, h, agraph, nei);
    hipLaunchKernelGGL(k_mg_out, dim3(157 * 2), dim3(256), 0, stream, fb, nei, BoT, bo, out);
}